// Round 7
// baseline (3326.810 us; speedup 1.0000x reference)
//
#include <hip/hip_runtime.h>
#include <stdint.h>

typedef _Float16 half_t;
typedef _Float16 half2_t __attribute__((ext_vector_type(2)));

#define TSEQ 2048
#define NB   32
#define HD   256
#define HN_ELEMS ((size_t)TSEQ*NB*HD)

static __device__ __forceinline__ float fdot2u(uint32_t a, uint32_t b, float acc) {
  return __builtin_amdgcn_fdot2(__builtin_bit_cast(half2_t, a),
                                __builtin_bit_cast(half2_t, b), acc, false);
}
static __device__ __forceinline__ float sigm_f(float x) {
  return __builtin_amdgcn_rcpf(1.0f + __expf(-x));
}
static __device__ __forceinline__ float tanh_f(float x) {
  return 2.0f * __builtin_amdgcn_rcpf(1.0f + __expf(-2.0f * x)) - 1.0f;
}

// ---------------------------------------------------------------------------
// Prep: fold zx into W, zh into U, cast to f16.
//  Wpk  : [kcG 0..31][1024 col][8 halfs]                 (gemm reg loads)
//  Upk3 : gates 0..2: [(c*2+kg)*16+kc][256 j][8 halfs]   (rec reg loads)
//  Ug4  : gate 3:     [kcG 0..31][256 j][8 halfs]        (rec LDS tile)
// bias = bW+bU (added to gemm output); zero h/c state.
// ---------------------------------------------------------------------------
__global__ void prep_kernel(const float* __restrict__ W, const float* __restrict__ U,
                            const float* __restrict__ bW, const float* __restrict__ bU,
                            const float* __restrict__ zx, const float* __restrict__ zh,
                            half_t* __restrict__ Wpk, half_t* __restrict__ Upk3,
                            half_t* __restrict__ Ug4, float* __restrict__ bias,
                            half_t* __restrict__ hstate, float* __restrict__ cstate) {
  int tid = blockIdx.x * 256 + threadIdx.x;   // (kcG 0..31) x (n 0..1023)
  int n   = tid & 1023;
  int kcG = tid >> 10;
  #pragma unroll
  for (int e = 0; e < 8; ++e) {
    int k = kcG * 8 + e;
    Wpk[((size_t)kcG * 1024 + n) * 8 + e] = (half_t)(W[n * 256 + k] * zx[k]);
    float uv = U[n * 256 + k] * zh[k];
    if (n < 768) {
      int c = n >> 8, j = n & 255, kg = kcG >> 4, kc = kcG & 15;
      Upk3[(((size_t)(c * 2 + kg) * 16 + kc) * 256 + j) * 8 + e] = (half_t)uv;
    } else {
      Ug4[((size_t)kcG * 256 + (n & 255)) * 8 + e] = (half_t)uv;
    }
  }
  if (kcG == 0) bias[n] = bW[n] + bU[n];
  if (tid < NB * HD) { hstate[tid] = (half_t)0.0f; cstate[tid] = 0.0f; }
}

// ---------------------------------------------------------------------------
// Input GEMM: 512 threads, 1 col/thread, full K=256 in 128 VGPRs.
// Static LDS pad -> 1 block/CU -> 256-reg budget; wreg asm-pinned per row
// so RA cannot rematerialize the weight loads inside the row loop.
// Output packed per j (gx[row][j][gate]) WITH bias pre-added.
// ---------------------------------------------------------------------------
__global__ __launch_bounds__(512)
__attribute__((amdgpu_waves_per_eu(2, 2)))
void gemm_kernel(const float* __restrict__ input, const uint4* __restrict__ Wpk,
                 const float* __restrict__ bias, half_t* __restrict__ gx, int row0) {
  __shared__ __align__(16) uint4 As[64 * 32];     // 64 rows x 256 halfs = 32KB
  __shared__ __align__(16) uint4 pad1b[4096];     // +64KB => 96KB: 1 block/CU
  const int tid = threadIdx.x;
  if ((int)blockIdx.x < 0) pad1b[tid] = As[tid];  // keep pad alive (never runs)
  const int halfsel = blockIdx.x & 1;
  const int rbase = (blockIdx.x >> 1) * 64;       // chunk-local row base
  const int col = halfsel * 512 + tid;

  uint32_t wreg[128];
  #pragma unroll
  for (int kc = 0; kc < 32; ++kc) {
    uint4 q = Wpk[(size_t)kc * 1024 + col];
    wreg[kc * 4 + 0] = q.x; wreg[kc * 4 + 1] = q.y;
    wreg[kc * 4 + 2] = q.z; wreg[kc * 4 + 3] = q.w;
  }
  const float bc = bias[col];
  #pragma unroll
  for (int i = 0; i < 8; ++i) {
    int lin = tid + i * 512;
    int row = lin >> 6, f4 = lin & 63;
    float4 v = ((const float4*)input)[((size_t)(row0 + rbase + row)) * 64 + f4];
    half2_t p0; p0[0] = (half_t)v.x; p0[1] = (half_t)v.y;
    half2_t p1; p1[0] = (half_t)v.z; p1[1] = (half_t)v.w;
    ((uint2*)As)[row * 64 + f4] = make_uint2(__builtin_bit_cast(uint32_t, p0),
                                             __builtin_bit_cast(uint32_t, p1));
  }
  __syncthreads();

  const int gate = col >> 8, j = col & 255;
  #pragma unroll 1
  for (int r = 0; r < 64; ++r) {
    // pin: forbid rematerializing wreg from memory inside this loop
    #pragma unroll
    for (int p = 0; p < 128; ++p) asm volatile("" : "+v"(wreg[p]));
    const uint4* arow = As + r * 32;
    float a0 = 0.f, a1 = 0.f;
    #pragma unroll
    for (int kc = 0; kc < 16; ++kc) {
      uint4 h0 = arow[2 * kc], h1 = arow[2 * kc + 1];
      a0 = fdot2u(wreg[8 * kc + 0], h0.x, a0);
      a0 = fdot2u(wreg[8 * kc + 1], h0.y, a0);
      a0 = fdot2u(wreg[8 * kc + 2], h0.z, a0);
      a0 = fdot2u(wreg[8 * kc + 3], h0.w, a0);
      a1 = fdot2u(wreg[8 * kc + 4], h1.x, a1);
      a1 = fdot2u(wreg[8 * kc + 5], h1.y, a1);
      a1 = fdot2u(wreg[8 * kc + 6], h1.z, a1);
      a1 = fdot2u(wreg[8 * kc + 7], h1.w, a1);
    }
    gx[((size_t)(rbase + r) * HD + j) * 4 + gate] = (half_t)(a0 + a1 + bc);
  }
}

// ---------------------------------------------------------------------------
// Recurrent kernel: 1 block = 1 batch chain = 1 CU. 512 threads =
// (kg K-half 0..1) x (j h-column 0..255) = 8 waves.
// Static LDS 135.6KB -> 1 block/CU -> 2 waves/EU -> 256-VGPR budget.
// ureg (gates i,f,o; 192 regs) is asm-pinned EVERY ITERATION: the empty
// "+v" asm redefines each value so RA cannot rematerialize it from L2
// inside the t-loop (the R1-R6 failure mode: VGPR_Count 64-128, U
// re-loaded every step). Gate g U in 128KB LDS, lane-consecutive b128.
// ---------------------------------------------------------------------------
__global__ __launch_bounds__(512)
__attribute__((amdgpu_waves_per_eu(2, 2)))
void rec_kernel(const half_t* __restrict__ gx, const uint4* __restrict__ Upk3,
                const uint4* __restrict__ Ug4,
                half_t* __restrict__ hstate, float* __restrict__ cstate,
                float* __restrict__ out, int tbase, int TB, int last) {
  __shared__ __align__(16) uint4  uglds[8192];     // gate-g U: 128KB
  __shared__ __align__(16) half_t hbuf[256];       // h_{t-1} as f16: 512B
  __shared__ __align__(16) float  part[4 * 256];   // kg1 partials: 4KB

  const int b   = blockIdx.x;
  const int tid = threadIdx.x;
  const int kg  = tid >> 8;
  const int j   = tid & 255;

  // stage gate-g U into LDS (one-time, coalesced, linear)
  #pragma unroll
  for (int i = 0; i < 16; ++i) uglds[i * 512 + tid] = Ug4[i * 512 + tid];

  uint32_t ureg[3][64];                            // gates i,f,o: 192 VGPRs
  #pragma unroll
  for (int c = 0; c < 3; ++c) {
    #pragma unroll
    for (int kc = 0; kc < 16; ++kc) {
      uint4 q = Upk3[((size_t)(c * 2 + kg) * 16 + kc) * 256 + j];
      ureg[c][kc * 4 + 0] = q.x; ureg[c][kc * 4 + 1] = q.y;
      ureg[c][kc * 4 + 2] = q.z; ureg[c][kc * 4 + 3] = q.w;
    }
  }

  float cc = 0.f;
  uint2 gpk = make_uint2(0, 0), npk = make_uint2(0, 0);
  const uint2* gpn = (const uint2*)gx + (size_t)b * HD + j;   // t=0 row
  float* outp = out + ((size_t)tbase * NB + b) * HD + j;
  if (kg == 0) {
    cc = cstate[b * HD + j];
    hbuf[j] = hstate[b * HD + j];
    gpk = *gpn;                                    // t=0 x-gates (bias folded)
  }
  gpn += (size_t)NB * HD;                          // points at t=1
  __syncthreads();

  #pragma unroll 1
  for (int t = 0; t < TB; ++t) {
    // pin: forbid rematerializing ureg from memory inside this loop
    #pragma unroll
    for (int c = 0; c < 3; ++c) {
      #pragma unroll
      for (int p = 0; p < 64; ++p) asm volatile("" : "+v"(ureg[c][p]));
    }

    if (kg == 0 && t + 1 < TB) npk = *gpn;         // prefetch next x-gates
    gpn += (size_t)NB * HD;

    float a0 = 0.f, a1 = 0.f, a2 = 0.f, a3 = 0.f;
    const uint4* hp  = (const uint4*)hbuf + kg * 16;    // this K-half of h
    const uint4* ugp = uglds + (size_t)kg * 16 * 256 + j;
    #pragma unroll
    for (int kc = 0; kc < 16; ++kc) {
      uint4 hv = hp[kc];                                // wave-uniform broadcast
      uint4 ug = ugp[kc * 256];                         // lane-consecutive
      a0 = fdot2u(ureg[0][kc * 4 + 0], hv.x, a0);
      a0 = fdot2u(ureg[0][kc * 4 + 1], hv.y, a0);
      a0 = fdot2u(ureg[0][kc * 4 + 2], hv.z, a0);
      a0 = fdot2u(ureg[0][kc * 4 + 3], hv.w, a0);
      a1 = fdot2u(ureg[1][kc * 4 + 0], hv.x, a1);
      a1 = fdot2u(ureg[1][kc * 4 + 1], hv.y, a1);
      a1 = fdot2u(ureg[1][kc * 4 + 2], hv.z, a1);
      a1 = fdot2u(ureg[1][kc * 4 + 3], hv.w, a1);
      a2 = fdot2u(ureg[2][kc * 4 + 0], hv.x, a2);
      a2 = fdot2u(ureg[2][kc * 4 + 1], hv.y, a2);
      a2 = fdot2u(ureg[2][kc * 4 + 2], hv.z, a2);
      a2 = fdot2u(ureg[2][kc * 4 + 3], hv.w, a2);
      a3 = fdot2u(ug.x, hv.x, a3);
      a3 = fdot2u(ug.y, hv.y, a3);
      a3 = fdot2u(ug.z, hv.z, a3);
      a3 = fdot2u(ug.w, hv.w, a3);
    }
    if (kg) {
      part[0 * 256 + j] = a0;
      part[1 * 256 + j] = a1;
      part[2 * 256 + j] = a2;
      part[3 * 256 + j] = a3;
    }
    __syncthreads();
    if (kg == 0) {
      half2_t g01 = __builtin_bit_cast(half2_t, gpk.x);
      half2_t g23 = __builtin_bit_cast(half2_t, gpk.y);
      a0 += part[0 * 256 + j] + (float)g01[0];
      a1 += part[1 * 256 + j] + (float)g01[1];
      a2 += part[2 * 256 + j] + (float)g23[0];
      a3 += part[3 * 256 + j] + (float)g23[1];
      float gi = sigm_f(a0), gf = sigm_f(a1), go = sigm_f(a2), gg = tanh_f(a3);
      cc = gf * cc + gi * gg;
      float h = go * tanh_f(cc);
      hbuf[j] = (half_t)h;
      *outp = h;
      if (last && t == TB - 1) {
        out[HN_ELEMS + (size_t)b * HD + j] = h;
        out[HN_ELEMS + (size_t)NB * HD + (size_t)b * HD + j] = cc;
      }
      gpk = npk;
    }
    outp += (size_t)NB * HD;
    __syncthreads();
  }
  if (kg == 0) {
    hstate[b * HD + j] = hbuf[j];
    cstate[b * HD + j] = cc;
  }
}

// ---------------------------------------------------------------------------
extern "C" void kernel_launch(void* const* d_in, const int* in_sizes, int n_in,
                              void* d_out, int out_size, void* d_ws, size_t ws_size,
                              hipStream_t stream) {
  const float* input = (const float*)d_in[0];
  const float* zx    = (const float*)d_in[1];
  const float* zh    = (const float*)d_in[2];
  const float* W     = (const float*)d_in[3];
  const float* bW    = (const float*)d_in[4];
  const float* U     = (const float*)d_in[5];
  const float* bU    = (const float*)d_in[6];
  float* out = (float*)d_out;

  char* ws = (char*)d_ws;
  uint4*  Upk3   = (uint4*)(ws);                           // 384 KB
  uint4*  Ug4    = (uint4*)(ws + (384 << 10));             // 128 KB
  uint4*  Wpk    = (uint4*)(ws + (512 << 10));             // 512 KB
  float*  bias   = (float*) (ws + (1 << 20));              // 4 KB
  half_t* hstate = (half_t*)(ws + (1 << 20) + (4 << 10));  // 16 KB
  float*  cstate = (float*) (ws + (1 << 20) + (20 << 10)); // 32 KB
  half_t* gx     = (half_t*)(ws + (2 << 20));              // TB*32*1024*2 B

  int TB = TSEQ;
  while (TB > 32 && (size_t)(2u << 20) + (size_t)TB * NB * 1024 * 2 > ws_size) TB >>= 1;

  prep_kernel<<<128, 256, 0, stream>>>(W, U, bW, bU, zx, zh,
                                       (half_t*)Wpk, (half_t*)Upk3, (half_t*)Ug4,
                                       bias, hstate, cstate);

  int nch = TSEQ / TB;
  for (int c = 0; c < nch; ++c) {
    int tbase = c * TB;
    gemm_kernel<<<(TB * NB / 64) * 2, 512, 0, stream>>>(input, Wpk, bias, gx, tbase * NB);
    rec_kernel<<<NB, 512, 0, stream>>>(gx, Upk3, Ug4, hstate, cstate, out,
                                       tbase, TB, (c == nch - 1) ? 1 : 0);
  }
}

// Round 8
// 3234.143 us; speedup vs baseline: 1.0287x; 1.0287x over previous
//
#include <hip/hip_runtime.h>
#include <stdint.h>

typedef _Float16 half_t;
typedef _Float16 half2_t __attribute__((ext_vector_type(2)));

#define TSEQ 2048
#define NB   32
#define HD   256
#define HN_ELEMS ((size_t)TSEQ*NB*HD)

static __device__ __forceinline__ float fdot2u(uint32_t a, uint32_t b, float acc) {
  return __builtin_amdgcn_fdot2(__builtin_bit_cast(half2_t, a),
                                __builtin_bit_cast(half2_t, b), acc, false);
}
static __device__ __forceinline__ float sigm_f(float x) {
  return __builtin_amdgcn_rcpf(1.0f + __expf(-x));
}
static __device__ __forceinline__ float tanh_f(float x) {
  return 2.0f * __builtin_amdgcn_rcpf(1.0f + __expf(-2.0f * x)) - 1.0f;
}

// ---------------------------------------------------------------------------
// Prep: fold zx into W, zh into U, cast to f16.
//  Wpk  : [kcG 0..31][1024 col][8 halfs]                 (gemm reg loads)
//  Upk3 : gates 0..2: [(c*2+kg)*16+kc][256 j][8 halfs]   (rec reg loads)
//  Ug4  : gate 3:     [kcG 0..31][256 j][8 halfs]        (rec LDS tile)
// bias = bW+bU (added to gemm output); zero h/c state.
// ---------------------------------------------------------------------------
__global__ void prep_kernel(const float* __restrict__ W, const float* __restrict__ U,
                            const float* __restrict__ bW, const float* __restrict__ bU,
                            const float* __restrict__ zx, const float* __restrict__ zh,
                            half_t* __restrict__ Wpk, half_t* __restrict__ Upk3,
                            half_t* __restrict__ Ug4, float* __restrict__ bias,
                            half_t* __restrict__ hstate, float* __restrict__ cstate) {
  int tid = blockIdx.x * 256 + threadIdx.x;   // (kcG 0..31) x (n 0..1023)
  int n   = tid & 1023;
  int kcG = tid >> 10;
  #pragma unroll
  for (int e = 0; e < 8; ++e) {
    int k = kcG * 8 + e;
    Wpk[((size_t)kcG * 1024 + n) * 8 + e] = (half_t)(W[n * 256 + k] * zx[k]);
    float uv = U[n * 256 + k] * zh[k];
    if (n < 768) {
      int c = n >> 8, j = n & 255, kg = kcG >> 4, kc = kcG & 15;
      Upk3[(((size_t)(c * 2 + kg) * 16 + kc) * 256 + j) * 8 + e] = (half_t)uv;
    } else {
      Ug4[((size_t)kcG * 256 + (n & 255)) * 8 + e] = (half_t)uv;
    }
  }
  if (kcG == 0) bias[n] = bW[n] + bU[n];
  if (tid < NB * HD) { hstate[tid] = (half_t)0.0f; cstate[tid] = 0.0f; }
}

// ---------------------------------------------------------------------------
// Input GEMM: 512 threads, 1 col/thread, full K=256 in 128 VGPRs.
// wreg values are load^rz (rz = runtime 0): NOT rematerializable, so the
// RA must keep them live instead of re-issuing the Wpk loads per row
// (the R1-R7 failure mode). Static LDS pad -> 1 block/CU -> 256-reg budget.
// Output packed per j (gx[row][j][gate]) WITH bias pre-added.
// ---------------------------------------------------------------------------
__global__ __launch_bounds__(512)
__attribute__((amdgpu_waves_per_eu(2, 2)))
void gemm_kernel(const float* __restrict__ input, const uint4* __restrict__ Wpk,
                 const float* __restrict__ bias, half_t* __restrict__ gx, int row0,
                 uint32_t rz) {
  __shared__ __align__(16) uint4 As[64 * 32];     // 64 rows x 256 halfs = 32KB
  __shared__ __align__(16) uint4 pad1b[4096];     // +64KB => 96KB: 1 block/CU
  const int tid = threadIdx.x;
  if ((int)blockIdx.x < 0) pad1b[tid] = As[tid];  // keep pad alive (never runs)
  const int halfsel = blockIdx.x & 1;
  const int rbase = (blockIdx.x >> 1) * 64;       // chunk-local row base
  const int col = halfsel * 512 + tid;

  uint32_t wreg[128];
  #pragma unroll
  for (int kc = 0; kc < 32; ++kc) {
    uint4 q = Wpk[(size_t)kc * 1024 + col];
    wreg[kc * 4 + 0] = q.x ^ rz; wreg[kc * 4 + 1] = q.y ^ rz;
    wreg[kc * 4 + 2] = q.z ^ rz; wreg[kc * 4 + 3] = q.w ^ rz;
  }
  const float bc = bias[col];
  #pragma unroll
  for (int i = 0; i < 8; ++i) {
    int lin = tid + i * 512;
    int row = lin >> 6, f4 = lin & 63;
    float4 v = ((const float4*)input)[((size_t)(row0 + rbase + row)) * 64 + f4];
    half2_t p0; p0[0] = (half_t)v.x; p0[1] = (half_t)v.y;
    half2_t p1; p1[0] = (half_t)v.z; p1[1] = (half_t)v.w;
    ((uint2*)As)[row * 64 + f4] = make_uint2(__builtin_bit_cast(uint32_t, p0),
                                             __builtin_bit_cast(uint32_t, p1));
  }
  __syncthreads();

  const int gate = col >> 8, j = col & 255;
  #pragma unroll 1
  for (int r = 0; r < 64; ++r) {
    const uint4* arow = As + r * 32;
    float a0 = 0.f, a1 = 0.f;
    #pragma unroll
    for (int kc = 0; kc < 16; ++kc) {
      uint4 h0 = arow[2 * kc], h1 = arow[2 * kc + 1];
      a0 = fdot2u(wreg[8 * kc + 0], h0.x, a0);
      a0 = fdot2u(wreg[8 * kc + 1], h0.y, a0);
      a0 = fdot2u(wreg[8 * kc + 2], h0.z, a0);
      a0 = fdot2u(wreg[8 * kc + 3], h0.w, a0);
      a1 = fdot2u(wreg[8 * kc + 4], h1.x, a1);
      a1 = fdot2u(wreg[8 * kc + 5], h1.y, a1);
      a1 = fdot2u(wreg[8 * kc + 6], h1.z, a1);
      a1 = fdot2u(wreg[8 * kc + 7], h1.w, a1);
    }
    gx[((size_t)(rbase + r) * HD + j) * 4 + gate] = (half_t)(a0 + a1 + bc);
  }
}

// ---------------------------------------------------------------------------
// Recurrent kernel: 1 block = 1 batch chain = 1 CU. 512 threads =
// (kg K-half 0..1) x (j h-column 0..255) = 8 waves.
// Static LDS 135.6KB -> 1 block/CU -> 2 waves/EU -> 256-VGPR budget.
// ureg values are load^rz (rz = runtime 0): the xor makes each value a
// load+alu chain, which LLVM cannot REMATERIALIZE inside the t-loop --
// the R1-R7 plateau was the allocator re-executing the invariant Upk3
// loads every step (reported VGPR 124 with U streamed from L2).
// Live set ~222 <= 256 budget -> U stays resident.
// Gate g U in 128KB LDS, lane-consecutive b128; h broadcast reads.
// ---------------------------------------------------------------------------
__global__ __launch_bounds__(512)
__attribute__((amdgpu_waves_per_eu(2, 2)))
void rec_kernel(const half_t* __restrict__ gx, const uint4* __restrict__ Upk3,
                const uint4* __restrict__ Ug4,
                half_t* __restrict__ hstate, float* __restrict__ cstate,
                float* __restrict__ out, int tbase, int TB, int last,
                uint32_t rz) {
  __shared__ __align__(16) uint4  uglds[8192];     // gate-g U: 128KB
  __shared__ __align__(16) half_t hbuf[256];       // h_{t-1} as f16: 512B
  __shared__ __align__(16) float  part[4 * 256];   // kg1 partials: 4KB

  const int b   = blockIdx.x;
  const int tid = threadIdx.x;
  const int kg  = tid >> 8;
  const int j   = tid & 255;

  // stage gate-g U into LDS (one-time, coalesced, linear)
  #pragma unroll
  for (int i = 0; i < 16; ++i) uglds[i * 512 + tid] = Ug4[i * 512 + tid];

  uint32_t ureg[3][64];                            // gates i,f,o: 192 VGPRs
  #pragma unroll
  for (int c = 0; c < 3; ++c) {
    #pragma unroll
    for (int kc = 0; kc < 16; ++kc) {
      uint4 q = Upk3[((size_t)(c * 2 + kg) * 16 + kc) * 256 + j];
      ureg[c][kc * 4 + 0] = q.x ^ rz; ureg[c][kc * 4 + 1] = q.y ^ rz;
      ureg[c][kc * 4 + 2] = q.z ^ rz; ureg[c][kc * 4 + 3] = q.w ^ rz;
    }
  }

  float cc = 0.f;
  uint2 gpk = make_uint2(0, 0), npk = make_uint2(0, 0);
  const uint2* gpn = (const uint2*)gx + (size_t)b * HD + j;   // t=0 row
  float* outp = out + ((size_t)tbase * NB + b) * HD + j;
  if (kg == 0) {
    cc = cstate[b * HD + j];
    hbuf[j] = hstate[b * HD + j];
    gpk = *gpn;                                    // t=0 x-gates (bias folded)
  }
  gpn += (size_t)NB * HD;                          // points at t=1
  __syncthreads();

  #pragma unroll 1
  for (int t = 0; t < TB; ++t) {
    if (kg == 0 && t + 1 < TB) npk = *gpn;         // prefetch next x-gates
    gpn += (size_t)NB * HD;

    float a0 = 0.f, a1 = 0.f, a2 = 0.f, a3 = 0.f;
    const uint4* hp  = (const uint4*)hbuf + kg * 16;    // this K-half of h
    const uint4* ugp = uglds + (size_t)kg * 16 * 256 + j;
    #pragma unroll
    for (int kc = 0; kc < 16; ++kc) {
      uint4 hv = hp[kc];                                // wave-uniform broadcast
      uint4 ug = ugp[kc * 256];                         // lane-consecutive
      a0 = fdot2u(ureg[0][kc * 4 + 0], hv.x, a0);
      a0 = fdot2u(ureg[0][kc * 4 + 1], hv.y, a0);
      a0 = fdot2u(ureg[0][kc * 4 + 2], hv.z, a0);
      a0 = fdot2u(ureg[0][kc * 4 + 3], hv.w, a0);
      a1 = fdot2u(ureg[1][kc * 4 + 0], hv.x, a1);
      a1 = fdot2u(ureg[1][kc * 4 + 1], hv.y, a1);
      a1 = fdot2u(ureg[1][kc * 4 + 2], hv.z, a1);
      a1 = fdot2u(ureg[1][kc * 4 + 3], hv.w, a1);
      a2 = fdot2u(ureg[2][kc * 4 + 0], hv.x, a2);
      a2 = fdot2u(ureg[2][kc * 4 + 1], hv.y, a2);
      a2 = fdot2u(ureg[2][kc * 4 + 2], hv.z, a2);
      a2 = fdot2u(ureg[2][kc * 4 + 3], hv.w, a2);
      a3 = fdot2u(ug.x, hv.x, a3);
      a3 = fdot2u(ug.y, hv.y, a3);
      a3 = fdot2u(ug.z, hv.z, a3);
      a3 = fdot2u(ug.w, hv.w, a3);
    }
    if (kg) {
      part[0 * 256 + j] = a0;
      part[1 * 256 + j] = a1;
      part[2 * 256 + j] = a2;
      part[3 * 256 + j] = a3;
    }
    __syncthreads();
    if (kg == 0) {
      half2_t g01 = __builtin_bit_cast(half2_t, gpk.x);
      half2_t g23 = __builtin_bit_cast(half2_t, gpk.y);
      a0 += part[0 * 256 + j] + (float)g01[0];
      a1 += part[1 * 256 + j] + (float)g01[1];
      a2 += part[2 * 256 + j] + (float)g23[0];
      a3 += part[3 * 256 + j] + (float)g23[1];
      float gi = sigm_f(a0), gf = sigm_f(a1), go = sigm_f(a2), gg = tanh_f(a3);
      cc = gf * cc + gi * gg;
      float h = go * tanh_f(cc);
      hbuf[j] = (half_t)h;
      *outp = h;
      if (last && t == TB - 1) {
        out[HN_ELEMS + (size_t)b * HD + j] = h;
        out[HN_ELEMS + (size_t)NB * HD + (size_t)b * HD + j] = cc;
      }
      gpk = npk;
    }
    outp += (size_t)NB * HD;
    __syncthreads();
  }
  if (kg == 0) {
    hstate[b * HD + j] = hbuf[j];
    cstate[b * HD + j] = cc;
  }
}

// ---------------------------------------------------------------------------
extern "C" void kernel_launch(void* const* d_in, const int* in_sizes, int n_in,
                              void* d_out, int out_size, void* d_ws, size_t ws_size,
                              hipStream_t stream) {
  const float* input = (const float*)d_in[0];
  const float* zx    = (const float*)d_in[1];
  const float* zh    = (const float*)d_in[2];
  const float* W     = (const float*)d_in[3];
  const float* bW    = (const float*)d_in[4];
  const float* U     = (const float*)d_in[5];
  const float* bU    = (const float*)d_in[6];
  float* out = (float*)d_out;

  char* ws = (char*)d_ws;
  uint4*  Upk3   = (uint4*)(ws);                           // 384 KB
  uint4*  Ug4    = (uint4*)(ws + (384 << 10));             // 128 KB
  uint4*  Wpk    = (uint4*)(ws + (512 << 10));             // 512 KB
  float*  bias   = (float*) (ws + (1 << 20));              // 4 KB
  half_t* hstate = (half_t*)(ws + (1 << 20) + (4 << 10));  // 16 KB
  float*  cstate = (float*) (ws + (1 << 20) + (20 << 10)); // 32 KB
  half_t* gx     = (half_t*)(ws + (2 << 20));              // TB*32*1024*2 B

  // runtime zero the compiler cannot see through (in_sizes[1] == 256 always;
  // 256 >> 9 == 0). Defeats rematerialization of the U/W register loads.
  uint32_t rz = (uint32_t)(in_sizes[1] >> 9);

  int TB = TSEQ;
  while (TB > 32 && (size_t)(2u << 20) + (size_t)TB * NB * 1024 * 2 > ws_size) TB >>= 1;

  prep_kernel<<<128, 256, 0, stream>>>(W, U, bW, bU, zx, zh,
                                       (half_t*)Wpk, (half_t*)Upk3, (half_t*)Ug4,
                                       bias, hstate, cstate);

  int nch = TSEQ / TB;
  for (int c = 0; c < nch; ++c) {
    int tbase = c * TB;
    gemm_kernel<<<(TB * NB / 64) * 2, 512, 0, stream>>>(input, Wpk, bias, gx,
                                                        tbase * NB, rz);
    rec_kernel<<<NB, 512, 0, stream>>>(gx, Upk3, Ug4, hstate, cstate, out,
                                       tbase, TB, (c == nch - 1) ? 1 : 0, rz);
  }
}